// Round 1
// baseline (848.740 us; speedup 1.0000x reference)
//
#include <hip/hip_runtime.h>
#include <math.h>

// PLANAttention: pyramid local attention.
//   top: (B,256,64,64), bot: (B,256,128,128), heads=8, kd=vd=32, ERF=3, stride=2
// Pipeline:
//   1) 6 projection GEMMs (256x256 weight @ feature map) -> tK,tQ,tV,bK,bQ,bV (ws)
//   2) attention kernel: per (b,h,pixel): M = K^T V (32x32), out = Q*M/sqrt(32)
//      q=0 -> top_ret; q=1..9 -> fold via atomicAdd into bot_ret
//   3) 2 fuse GEMMs -> d_out
// ws layout (fp32): tK,tQ,tV (2*256*4096 each), bK,bQ,bV (2*256*16384 each),
//                   top_ret (2*256*4096), bot_ret (2*256*16384)  == 160 MiB total.

#define HEADS 8

// Y[b,o,s] = sum_c W[o,c] * X[b,c,s]   (o,c = 256; batch stride 256*S)
__global__ __launch_bounds__(256) void gemm_wx(
    const float* __restrict__ W, const float* __restrict__ X,
    float* __restrict__ Y, int S)
{
    const int b  = blockIdx.z;
    const int o0 = blockIdx.y * 64;
    const int s0 = blockIdx.x * 64;
    const float* Xb = X + (size_t)b * 256 * S;
    float*       Yb = Y + (size_t)b * 256 * S;

    __shared__ float Wt[16][68];  // [c][o]  (+pad: 68*4B = 272B, 16B-aligned rows)
    __shared__ float Xt[16][68];  // [c][s]

    const int tid = threadIdx.x;
    const int tx = tid & 15, ty = tid >> 4;

    float acc[4][4] = {};

    for (int c0 = 0; c0 < 256; c0 += 16) {
        // W tile: 64(o) x 16(c), stored transposed Wt[c][o]
        {
            int l = tid;
            #pragma unroll
            for (int it = 0; it < 4; ++it, l += 256) {
                int row = l >> 4, col = l & 15;
                Wt[col][row] = W[(o0 + row) * 256 + c0 + col];
            }
        }
        // X tile: 16(c) x 64(s)
        {
            int l = tid;
            #pragma unroll
            for (int it = 0; it < 4; ++it, l += 256) {
                int row = l >> 6, col = l & 63;
                Xt[row][col] = Xb[(size_t)(c0 + row) * S + s0 + col];
            }
        }
        __syncthreads();
        #pragma unroll
        for (int kk = 0; kk < 16; ++kk) {
            float a[4], bb[4];
            #pragma unroll
            for (int i = 0; i < 4; ++i) a[i] = Wt[kk][ty * 4 + i];
            #pragma unroll
            for (int j = 0; j < 4; ++j) bb[j] = Xt[kk][tx * 4 + j];
            #pragma unroll
            for (int i = 0; i < 4; ++i)
                #pragma unroll
                for (int j = 0; j < 4; ++j)
                    acc[i][j] += a[i] * bb[j];
        }
        __syncthreads();
    }
    #pragma unroll
    for (int i = 0; i < 4; ++i) {
        float4 v = make_float4(acc[i][0], acc[i][1], acc[i][2], acc[i][3]);
        *(float4*)&Yb[(size_t)(o0 + ty * 4 + i) * S + s0 + tx * 4] = v;
    }
}

// One block = 8 pixels x 32 lanes, for fixed (b, head).
// Phase 1 (lane=d): M[d][v] = sum_k K[k][d]*V[k][v]  -> LDS
// Phase 2 (lane=v): out[q][v] = (sum_d Q[q][d]*M[d][v]) / sqrt(32)
__global__ __launch_bounds__(256) void attn_kernel(
    const float* __restrict__ tK, const float* __restrict__ tQ, const float* __restrict__ tV,
    const float* __restrict__ bK, const float* __restrict__ bQ, const float* __restrict__ bV,
    float* __restrict__ top_ret, float* __restrict__ bot_ret)
{
    const int b = blockIdx.z, h = blockIdx.y;
    const int tid  = threadIdx.x;
    const int pl   = tid >> 5;          // local pixel 0..7
    const int lane = tid & 31;
    const int pix  = blockIdx.x * 8 + pl;   // 0..4095
    const int y = pix >> 6, x = pix & 63;

    __shared__ float M[8][32][33];      // +1 pad: banks (d*33+v)%32 distinct over d

    const size_t tBase = ((size_t)b * 256 + h * 32);   // channel base (top: *4096, bot: *16384)

    // ---- Phase 1: lane = d ----
    {
        const int d = lane;
        float m[32];
        #pragma unroll
        for (int v = 0; v < 32; ++v) m[v] = 0.f;

        #pragma unroll
        for (int k = 0; k < 10; ++k) {
            if (k == 0) {
                float kv = tK[(tBase + d) * 4096 + pix];
                #pragma unroll
                for (int v = 0; v < 32; ++v)
                    m[v] += kv * tV[(tBase + v) * 4096 + pix];
            } else {
                int i = (k - 1) / 3, j = (k - 1) % 3;
                int by = 2 * y + i - 1, bx = 2 * x + j - 1;
                if ((unsigned)by < 128u && (unsigned)bx < 128u) {
                    int bpix = by * 128 + bx;
                    float kv = bK[(tBase + d) * 16384 + bpix];
                    #pragma unroll
                    for (int v = 0; v < 32; ++v)
                        m[v] += kv * bV[(tBase + v) * 16384 + bpix];
                }
            }
        }
        #pragma unroll
        for (int v = 0; v < 32; ++v) M[pl][d][v] = m[v];
    }
    __syncthreads();

    // ---- Phase 2: lane = v ----
    {
        const int v = lane;
        const float scale = 0.17677669529663687f;  // 1/sqrt(32)
        #pragma unroll
        for (int q = 0; q < 10; ++q) {
            if (q == 0) {
                float acc = 0.f;
                #pragma unroll
                for (int dd = 0; dd < 32; ++dd)
                    acc += tQ[(tBase + dd) * 4096 + pix] * M[pl][dd][v];
                top_ret[(tBase + v) * 4096 + pix] = acc * scale;
            } else {
                int i = (q - 1) / 3, j = (q - 1) % 3;
                int by = 2 * y + i - 1, bx = 2 * x + j - 1;
                if ((unsigned)by < 128u && (unsigned)bx < 128u) {
                    int bpix = by * 128 + bx;
                    float acc = 0.f;
                    #pragma unroll
                    for (int dd = 0; dd < 32; ++dd)
                        acc += bQ[(tBase + dd) * 16384 + bpix] * M[pl][dd][v];
                    atomicAdd(&bot_ret[(tBase + v) * 16384 + bpix], acc * scale);
                }
            }
        }
    }
}

extern "C" void kernel_launch(void* const* d_in, const int* in_sizes, int n_in,
                              void* d_out, int out_size, void* d_ws, size_t ws_size,
                              hipStream_t stream) {
    const float* top_feat    = (const float*)d_in[0];
    const float* bot_feat    = (const float*)d_in[1];
    const float* W_top_key   = (const float*)d_in[2];
    const float* W_top_query = (const float*)d_in[3];
    const float* W_top_value = (const float*)d_in[4];
    const float* W_bot_key   = (const float*)d_in[5];
    const float* W_bot_query = (const float*)d_in[6];
    const float* W_bot_value = (const float*)d_in[7];
    const float* W_top_fuse  = (const float*)d_in[8];
    const float* W_bot_fuse  = (const float*)d_in[9];

    float* out     = (float*)d_out;
    float* top_out = out;                          // (2,256,64,64)
    float* bot_out = out + (size_t)2 * 256 * 4096; // (2,256,128,128)

    const size_t TOPSZ = (size_t)2 * 256 * 4096;    // 2,097,152 floats
    const size_t BOTSZ = (size_t)2 * 256 * 16384;   // 8,388,608 floats
    float* ws = (float*)d_ws;
    float* tK = ws;            float* tQ = tK + TOPSZ;  float* tV = tQ + TOPSZ;
    float* bK = tV + TOPSZ;    float* bQ = bK + BOTSZ;  float* bV = bQ + BOTSZ;
    float* top_ret = bV + BOTSZ;
    float* bot_ret = top_ret + TOPSZ;

    dim3 blk(256);
    // projections
    gemm_wx<<<dim3(64, 4, 2),  blk, 0, stream>>>(W_top_key,   top_feat, tK, 4096);
    gemm_wx<<<dim3(64, 4, 2),  blk, 0, stream>>>(W_top_query, top_feat, tQ, 4096);
    gemm_wx<<<dim3(64, 4, 2),  blk, 0, stream>>>(W_top_value, top_feat, tV, 4096);
    gemm_wx<<<dim3(256, 4, 2), blk, 0, stream>>>(W_bot_key,   bot_feat, bK, 16384);
    gemm_wx<<<dim3(256, 4, 2), blk, 0, stream>>>(W_bot_query, bot_feat, bQ, 16384);
    gemm_wx<<<dim3(256, 4, 2), blk, 0, stream>>>(W_bot_value, bot_feat, bV, 16384);

    // fold target must be zero each call (atomics accumulate)
    hipMemsetAsync(bot_ret, 0, BOTSZ * sizeof(float), stream);

    attn_kernel<<<dim3(512, HEADS, 2), blk, 0, stream>>>(tK, tQ, tV, bK, bQ, bV,
                                                         top_ret, bot_ret);
    // fuse
    gemm_wx<<<dim3(64, 4, 2),  blk, 0, stream>>>(W_top_fuse, top_ret, top_out, 4096);
    gemm_wx<<<dim3(256, 4, 2), blk, 0, stream>>>(W_bot_fuse, bot_ret, bot_out, 16384);
}

// Round 2
// 125.102 us; speedup vs baseline: 6.7844x; 6.7844x over previous
//
#include <hip/hip_runtime.h>
#include <hip/hip_bf16.h>
#include <math.h>

// PLANAttention, bf16/MFMA pipeline:
//  1) k_cvt_w: 8 weight mats fp32 -> bf16 (Wb, order: tK,tQ,tV,bK,bQ,bV,tF,bF)
//  2) k_transpose_cvt: feat (B,256,S) fp32 -> featT (B,S,256) bf16   (top+bot)
//  3) k_gemm<0>: fused QKV proj: C[m=pixrow][n=o(768)] = featT . Wqkv^T -> pixel-major bf16
//  4) k_attn: per (pixel,head) wave: S=Q.K^T (1 mfma), O=S.V (2 mfma)
//       q=0 -> tRet bf16 (B,S,256); q=1..9 -> pat bf16 [b][h][9][4096][32]
//  5) k_fold: pat -> botRet bf16 (B,Sb,256) (gather <=4 windows, no atomics)
//  6) k_gemm<1>: fuse: C[m=o][n=pixrow] = Wfuse . ret^T -> channel-major fp32 d_out

typedef __attribute__((ext_vector_type(8))) short  bh8;
typedef __attribute__((ext_vector_type(4))) short  bh4;
typedef __attribute__((ext_vector_type(4))) float  f32x4;
typedef unsigned short u16;

static __device__ __forceinline__ u16 f2b(float x) {
    __hip_bfloat16 h = __float2bfloat16(x);
    return __builtin_bit_cast(u16, h);
}
static __device__ __forceinline__ float b2f(u16 u) {
    unsigned v = ((unsigned)u) << 16;
    return __builtin_bit_cast(float, v);
}

// ---------------- weight convert: 8 x 256x256 fp32 -> bf16 ----------------
__global__ __launch_bounds__(256) void k_cvt_w(
    const float* w0, const float* w1, const float* w2, const float* w3,
    const float* w4, const float* w5, const float* w6, const float* w7,
    u16* __restrict__ Wb)
{
    const float* srcs[8] = {w0,w1,w2,w3,w4,w5,w6,w7};
    const float* src = srcs[blockIdx.y];
    int i = (blockIdx.x * 256 + threadIdx.x) * 4;
    float4 v = *(const float4*)&src[i];
    u16 tmp[4] = { f2b(v.x), f2b(v.y), f2b(v.z), f2b(v.w) };
    *(uint2*)&Wb[(size_t)blockIdx.y * 65536 + i] = *(uint2*)tmp;
}

// ---------------- transpose + convert: (B,256,S) f32 -> (B,S,256) bf16 ----------------
__global__ __launch_bounds__(256) void k_transpose_cvt(
    const float* __restrict__ in, u16* __restrict__ out, int S)
{
    const int b  = blockIdx.z;
    const int s0 = blockIdx.x * 64, c0 = blockIdx.y * 64;
    in  += (size_t)b * 256 * S;
    out += (size_t)b * S * 256;
    __shared__ float T[64][65];
    const int t = threadIdx.x;
    {
        int cc = t >> 4, f4 = t & 15;
        #pragma unroll
        for (int rep = 0; rep < 4; ++rep) {
            int c = cc + rep * 16;
            float4 v = *(const float4*)&in[(size_t)(c0 + c) * S + s0 + f4 * 4];
            T[c][f4*4+0] = v.x; T[c][f4*4+1] = v.y;
            T[c][f4*4+2] = v.z; T[c][f4*4+3] = v.w;
        }
    }
    __syncthreads();
    {
        int sr = t >> 3, u = t & 7;
        #pragma unroll
        for (int rep = 0; rep < 2; ++rep) {
            int s = sr + rep * 32;
            u16 tmp[8];
            #pragma unroll
            for (int e = 0; e < 8; ++e) tmp[e] = f2b(T[u*8+e][s]);
            *(uint4*)&out[(size_t)(s0 + s) * 256 + c0 + u * 8] = *(uint4*)tmp;
        }
    }
}

// ---------------- bf16 GEMM: C[m][n] = sum_k A[m][k]*B[n][k], K=256 ----------------
// tile: BM=64 (m0=blockIdx.y*64), BN=256 (n0=blockIdx.x*256), BK=64, 4 waves split N.
// MODE 0 (proj): store bf16 at Yp[(n>>8)*arrsz + m*256 + (n&255)]
// MODE 1 (fuse): store f32 at  Yf[((b*256 + m)<<lgS) + s], b=n>>lgS, s=n&(S-1)
template<int MODE>
__global__ __launch_bounds__(256) void k_gemm(
    const u16* __restrict__ A, const u16* __restrict__ B,
    void* __restrict__ Yv, size_t arrsz, int lgS)
{
    const int n0 = blockIdx.x * 256;
    const int m0 = blockIdx.y * 64;
    const int t  = threadIdx.x;
    const int w  = t >> 6, wl = t & 63, l16 = wl & 15, grp = wl >> 4;

    __shared__ __align__(16) u16 AT[64 * 72];
    __shared__ __align__(16) u16 BT[256 * 72];

    f32x4 acc[4][4];
    #pragma unroll
    for (int i = 0; i < 4; ++i)
        #pragma unroll
        for (int j = 0; j < 4; ++j) acc[i][j] = (f32x4){0.f, 0.f, 0.f, 0.f};

    for (int kk = 0; kk < 256; kk += 64) {
        #pragma unroll
        for (int it = 0; it < 2; ++it) {
            int c = t + it * 256;
            int row = c >> 3, u = c & 7;
            uint4 v = *(const uint4*)&A[(size_t)(m0 + row) * 256 + kk + u * 8];
            *(uint4*)&AT[row * 72 + u * 8] = v;
        }
        #pragma unroll
        for (int it = 0; it < 8; ++it) {
            int c = t + it * 256;
            int row = c >> 3, u = c & 7;
            uint4 v = *(const uint4*)&B[(size_t)(n0 + row) * 256 + kk + u * 8];
            *(uint4*)&BT[row * 72 + u * 8] = v;
        }
        __syncthreads();
        #pragma unroll
        for (int ks = 0; ks < 2; ++ks) {
            bh8 af[4], bf[4];
            #pragma unroll
            for (int mi = 0; mi < 4; ++mi)
                af[mi] = *(const bh8*)&AT[(mi*16 + l16) * 72 + ks*32 + grp*8];
            #pragma unroll
            for (int ni = 0; ni < 4; ++ni)
                bf[ni] = *(const bh8*)&BT[(w*64 + ni*16 + l16) * 72 + ks*32 + grp*8];
            #pragma unroll
            for (int mi = 0; mi < 4; ++mi)
                #pragma unroll
                for (int ni = 0; ni < 4; ++ni)
                    acc[mi][ni] = __builtin_amdgcn_mfma_f32_16x16x32_bf16(
                        af[mi], bf[ni], acc[mi][ni], 0, 0, 0);
        }
        __syncthreads();
    }

    // epilogue: C[m][n], m = m0+mi*16+grp*4+r, n = n0+w*64+ni*16+l16
    #pragma unroll
    for (int mi = 0; mi < 4; ++mi)
        #pragma unroll
        for (int ni = 0; ni < 4; ++ni)
            #pragma unroll
            for (int r = 0; r < 4; ++r) {
                int m = m0 + mi*16 + grp*4 + r;
                int n = n0 + w*64 + ni*16 + l16;
                float val = acc[mi][ni][r];
                if (MODE == 0) {
                    u16* Yp = (u16*)Yv;
                    Yp[(size_t)(n >> 8) * arrsz + (size_t)m * 256 + (n & 255)] = f2b(val);
                } else {
                    float* Yf = (float*)Yv;
                    int bb = n >> lgS, s = n & ((1 << lgS) - 1);
                    Yf[(((size_t)bb * 256 + m) << lgS) + s] = val;
                }
            }
}

// ---------------- attention: one wave per (pixel, head) ----------------
__global__ __launch_bounds__(256) void k_attn(
    const u16* __restrict__ tK, const u16* __restrict__ tQ, const u16* __restrict__ tV,
    const u16* __restrict__ bK, const u16* __restrict__ bQ, const u16* __restrict__ bV,
    u16* __restrict__ tRet, u16* __restrict__ pat)
{
    const int pix = blockIdx.x;     // 0..4095
    const int b   = blockIdx.y;
    const int w   = threadIdx.x >> 6;
    const int wl  = threadIdx.x & 63;
    const int l16 = wl & 15, grp = wl >> 4;
    const int y = pix >> 6, x = pix & 63;

    __shared__ u16 Ssm[4][16][24];        // [wave][q][kpos], stride 48B
    __shared__ __align__(16) u16 Vsm[4][2][16][16]; // [wave][v-half][kpos][v16]

    // position p = l16: p=0 top pixel, p=1..9 bot neighbor, p>=10 pad
    const int p = l16;
    bool pvalid = false; int bpix = 0; const bool istop = (p == 0);
    if (p == 0) pvalid = true;
    else if (p < 10) {
        int pm = p - 1; int i = (pm * 11) >> 5; int j = pm - 3 * i;
        int by = 2 * y + i - 1, bx = 2 * x + j - 1;
        pvalid = ((unsigned)by < 128u) && ((unsigned)bx < 128u);
        bpix = by * 128 + bx;
    }
    const size_t topRow = ((size_t)b * 4096  + pix)  * 256;
    const size_t botRow = ((size_t)b * 16384 + bpix) * 256;
    const float scale = 0.17677669529663687f; // 1/sqrt(32)

    #pragma unroll
    for (int hi = 0; hi < 2; ++hi) {
        const int h = w + hi * 4;
        const size_t off = (istop ? topRow : botRow) + h * 32 + grp * 8;
        bh8 aQ = {}, aK = {}, vV = {};
        if (pvalid) {
            if (istop) {
                aQ = *(const bh8*)(tQ + off);
                aK = *(const bh8*)(tK + off);
                vV = *(const bh8*)(tV + off);
            } else {
                aQ = *(const bh8*)(bQ + off);
                aK = *(const bh8*)(bK + off);
                vV = *(const bh8*)(bV + off);
            }
        }
        // stage V rows (zeros for invalid rows): half = grp>>1, chunk (grp&1)*8
        *(bh8*)&Vsm[w][grp >> 1][p][(grp & 1) * 8] = vV;

        // S = Q.K^T   (A rows = query pos, B cols = key pos, k = d contiguous)
        f32x4 z = {0.f, 0.f, 0.f, 0.f};
        f32x4 sC = __builtin_amdgcn_mfma_f32_16x16x32_bf16(aQ, aK, z, 0, 0, 0);
        #pragma unroll
        for (int r = 0; r < 4; ++r)
            Ssm[w][grp * 4 + r][l16] = f2b(sC[r] * scale);

        // A_S: row q=l16, k-slots (grp,i<4) = kpos 4*grp+i ; slots i>=4 zero
        bh8 aS = {};
        *(bh4*)&aS = *(const bh4*)&Ssm[w][l16][grp * 4];

        // B_V: slot (grp,i<4) = V[kpos=4*grp+i][v], consistent with A_S labeling
        bh8 bv0 = {}, bv1 = {};
        #pragma unroll
        for (int j = 0; j < 4; ++j) {
            bv0[j] = (short)Vsm[w][0][grp * 4 + j][l16];
            bv1[j] = (short)Vsm[w][1][grp * 4 + j][l16];
        }
        f32x4 oc0 = __builtin_amdgcn_mfma_f32_16x16x32_bf16(aS, bv0, z, 0, 0, 0);
        f32x4 oc1 = __builtin_amdgcn_mfma_f32_16x16x32_bf16(aS, bv1, z, 0, 0, 0);

        // outputs: row q = grp*4+r, col v = l16 (+16 for oc1)
        if (grp == 0) {
            size_t o = topRow + (size_t)h * 32;
            tRet[o + l16]      = f2b(oc0[0]);
            tRet[o + 16 + l16] = f2b(oc1[0]);
        }
        #pragma unroll
        for (int r = 0; r < 4; ++r) {
            int q = grp * 4 + r;
            if (q >= 1 && q <= 9) {
                size_t base = ((((size_t)b * 8 + h) * 9 + (q - 1)) * 4096 + pix) * 32;
                pat[base + l16]      = f2b(oc0[r]);
                pat[base + 16 + l16] = f2b(oc1[r]);
            }
        }
    }
}

// ---------------- fold: pat [b][h][9][4096][32] -> botRet (B,16384,256) bf16 ----------------
__global__ __launch_bounds__(256) void k_fold(
    const u16* __restrict__ pat, u16* __restrict__ botRet)
{
    int tid = blockIdx.x * 256 + threadIdx.x;       // 1,048,576 threads
    int vchunk = tid & 3;                           // 8 v's each
    int ri = tid >> 2;                              // (b*16384 + bpix)*8 + h
    int b = ri >> 17;
    int bpix = (ri >> 3) & 16383;
    int h = ri & 7;
    int by = bpix >> 7, bx = bpix & 127;
    int v0 = vchunk * 8;

    float acc[8];
    #pragma unroll
    for (int e = 0; e < 8; ++e) acc[e] = 0.f;

    for (int iy = 0; iy < 3; ++iy) {
        int ty = by + 1 - iy;
        if (ty & 1) continue;
        int yy = ty >> 1;
        if ((unsigned)yy >= 64u) continue;
        for (int jx = 0; jx < 3; ++jx) {
            int tx = bx + 1 - jx;
            if (tx & 1) continue;
            int xx = tx >> 1;
            if ((unsigned)xx >= 64u) continue;
            int q = iy * 3 + jx;
            size_t addr = ((((size_t)b * 8 + h) * 9 + q) * 4096 + (yy * 64 + xx)) * 32 + v0;
            uint4 pv = *(const uint4*)&pat[addr];
            const u16* pp = (const u16*)&pv;
            #pragma unroll
            for (int e = 0; e < 8; ++e) acc[e] += b2f(pp[e]);
        }
    }
    u16 tmp[8];
    #pragma unroll
    for (int e = 0; e < 8; ++e) tmp[e] = f2b(acc[e]);
    *(uint4*)&botRet[((size_t)b * 16384 + bpix) * 256 + h * 32 + v0] = *(uint4*)tmp;
}

extern "C" void kernel_launch(void* const* d_in, const int* in_sizes, int n_in,
                              void* d_out, int out_size, void* d_ws, size_t ws_size,
                              hipStream_t stream) {
    const float* top_feat = (const float*)d_in[0];
    const float* bot_feat = (const float*)d_in[1];

    float* out     = (float*)d_out;
    float* top_out = out;                            // (2,256,64,64)
    float* bot_out = out + (size_t)2 * 256 * 4096;   // (2,256,128,128)

    const size_t TOPU = (size_t)2 * 4096  * 256;   // ushort counts
    const size_t BOTU = (size_t)2 * 16384 * 256;
    char* p = (char*)d_ws;
    u16* Wb     = (u16*)p;  p += (size_t)8 * 65536 * 2;   // 1.0 MB
    u16* topT   = (u16*)p;  p += TOPU * 2;                // 4.2 MB
    u16* botT   = (u16*)p;  p += BOTU * 2;                // 16.8 MB
    u16* tK     = (u16*)p;  p += TOPU * 2;
    u16* tQ     = (u16*)p;  p += TOPU * 2;
    u16* tV     = (u16*)p;  p += TOPU * 2;                // 12.6 MB
    u16* bK     = (u16*)p;  p += BOTU * 2;
    u16* bQ     = (u16*)p;  p += BOTU * 2;
    u16* bV     = (u16*)p;  p += BOTU * 2;                // 50.3 MB
    u16* tRet   = (u16*)p;  p += TOPU * 2;                // 4.2 MB
    u16* pat    = (u16*)p;  p += (size_t)2*8*9*4096*32*2; // 37.7 MB
    u16* botRet = (u16*)p;  p += BOTU * 2;                // 16.8 MB  (total ~143.7 MB)

    dim3 blk(256);

    // weights -> bf16 (order: tK,tQ,tV,bK,bQ,bV,tFuse,bFuse)
    k_cvt_w<<<dim3(64, 8), blk, 0, stream>>>(
        (const float*)d_in[2], (const float*)d_in[3], (const float*)d_in[4],
        (const float*)d_in[5], (const float*)d_in[6], (const float*)d_in[7],
        (const float*)d_in[8], (const float*)d_in[9], Wb);

    // feat transpose+convert
    k_transpose_cvt<<<dim3(64, 4, 2),  blk, 0, stream>>>(top_feat, topT, 4096);
    k_transpose_cvt<<<dim3(256, 4, 2), blk, 0, stream>>>(bot_feat, botT, 16384);

    // fused QKV projections (N = 768 = [K|Q|V] each 256 wide)
    k_gemm<0><<<dim3(3, 128), blk, 0, stream>>>(topT, Wb,              (void*)tK, TOPU, 0);
    k_gemm<0><<<dim3(3, 512), blk, 0, stream>>>(botT, Wb + 3*65536,    (void*)bK, BOTU, 0);

    // attention
    k_attn<<<dim3(4096, 2), blk, 0, stream>>>(tK, tQ, tV, bK, bQ, bV, tRet, pat);

    // fold bot windows
    k_fold<<<dim3(4096), blk, 0, stream>>>(pat, botRet);

    // fuse GEMMs -> fp32 channel-major outputs
    k_gemm<1><<<dim3(32, 4),  blk, 0, stream>>>(Wb + 6*65536, tRet,   (void*)top_out, 0, 12);
    k_gemm<1><<<dim3(128, 4), blk, 0, stream>>>(Wb + 7*65536, botRet, (void*)bot_out, 0, 14);
}

// Round 3
// 112.620 us; speedup vs baseline: 7.5363x; 1.1108x over previous
//
#include <hip/hip_runtime.h>
#include <hip/hip_bf16.h>
#include <math.h>

// PLANAttention, bf16/MFMA pipeline (round 3: gload_lds + XOR-swizzle + 2-phase GEMM):
//  1) k_cvt_w: 8 weight mats fp32 -> bf16 (Wb, order: tK,tQ,tV,bK,bQ,bV,tF,bF)
//  2) k_transpose_cvt: feat (B,256,S) fp32 -> featT (B,S,256) bf16   (top+bot)
//  3) k_gemm<0>: fused QKV proj: C[m=pixrow][n=o(768)] = featT . Wqkv^T -> pixel-major bf16
//  4) k_attn: per (pixel,head) wave: S=Q.K^T (1 mfma), O=S.V (2 mfma)
//       q=0 -> tRet bf16 (B,S,256); q=1..9 -> pat bf16 [b][h][9][4096][32]
//  5) k_fold: pat -> botRet bf16 (B,Sb,256) (gather <=4 windows, no atomics)
//  6) k_gemm<1>: fuse: C[m=o][n=pixrow] = Wfuse . ret^T -> channel-major fp32 d_out

typedef __attribute__((ext_vector_type(8))) short  bh8;
typedef __attribute__((ext_vector_type(4))) short  bh4;
typedef __attribute__((ext_vector_type(4))) float  f32x4;
typedef unsigned short u16;

static __device__ __forceinline__ u16 f2b(float x) {
    __hip_bfloat16 h = __float2bfloat16(x);
    return __builtin_bit_cast(u16, h);
}
static __device__ __forceinline__ float b2f(u16 u) {
    unsigned v = ((unsigned)u) << 16;
    return __builtin_bit_cast(float, v);
}

// async global->LDS, 16B per lane. Dest must be linear in lane (wave-uniform base + lane*16).
static __device__ __forceinline__ void gload16(const u16* g, u16* l) {
    __builtin_amdgcn_global_load_lds(
        (const __attribute__((address_space(1))) unsigned int*)g,
        (__attribute__((address_space(3))) unsigned int*)l, 16, 0, 0);
}

// ---------------- weight convert: 8 x 256x256 fp32 -> bf16 ----------------
__global__ __launch_bounds__(256) void k_cvt_w(
    const float* w0, const float* w1, const float* w2, const float* w3,
    const float* w4, const float* w5, const float* w6, const float* w7,
    u16* __restrict__ Wb)
{
    const float* srcs[8] = {w0,w1,w2,w3,w4,w5,w6,w7};
    const float* src = srcs[blockIdx.y];
    int i = (blockIdx.x * 256 + threadIdx.x) * 4;
    float4 v = *(const float4*)&src[i];
    u16 tmp[4] = { f2b(v.x), f2b(v.y), f2b(v.z), f2b(v.w) };
    *(uint2*)&Wb[(size_t)blockIdx.y * 65536 + i] = *(uint2*)tmp;
}

// ---------------- transpose + convert: (B,256,S) f32 -> (B,S,256) bf16 ----------------
__global__ __launch_bounds__(256) void k_transpose_cvt(
    const float* __restrict__ in, u16* __restrict__ out, int S)
{
    const int b  = blockIdx.z;
    const int s0 = blockIdx.x * 64, c0 = blockIdx.y * 64;
    in  += (size_t)b * 256 * S;
    out += (size_t)b * S * 256;
    __shared__ float T[64][65];
    const int t = threadIdx.x;
    {
        int cc = t >> 4, f4 = t & 15;
        #pragma unroll
        for (int rep = 0; rep < 4; ++rep) {
            int c = cc + rep * 16;
            float4 v = *(const float4*)&in[(size_t)(c0 + c) * S + s0 + f4 * 4];
            T[c][f4*4+0] = v.x; T[c][f4*4+1] = v.y;
            T[c][f4*4+2] = v.z; T[c][f4*4+3] = v.w;
        }
    }
    __syncthreads();
    {
        int sr = t >> 3, u = t & 7;
        #pragma unroll
        for (int rep = 0; rep < 2; ++rep) {
            int s = sr + rep * 32;
            u16 tmp[8];
            #pragma unroll
            for (int e = 0; e < 8; ++e) tmp[e] = f2b(T[u*8+e][s]);
            *(uint4*)&out[(size_t)(s0 + s) * 256 + c0 + u * 8] = *(uint4*)tmp;
        }
    }
}

// ---------------- bf16 GEMM: C[m][n] = sum_k A[m][k]*B[n][k], K=256 ----------------
// BM=64 (m0=blockIdx.y*64), BN=256 (n0=blockIdx.x*256), BK=64, 4 waves split N.
// Staging: global_load_lds dwordx4, double-buffered, 1 barrier per K-tile.
// LDS rows are 128B (64 bf16); 16B-chunk index XOR-swizzled by (row&7) on BOTH
// the global source (pre-swizzle) and the ds_read (T2 / rule 21).
// MODE 0 (proj): store bf16 at Yp[(n>>8)*arrsz + m*256 + (n&255)]
// MODE 1 (fuse): store f32 at  Yf[((b*256 + m)<<lgS) + s], b=n>>lgS, s=n&(S-1)
template<int MODE>
__global__ __launch_bounds__(256) void k_gemm(
    const u16* __restrict__ A, const u16* __restrict__ B,
    void* __restrict__ Yv, size_t arrsz, int lgS)
{
    const int n0 = blockIdx.x * 256;
    const int m0 = blockIdx.y * 64;
    const int t  = threadIdx.x;
    const int w  = t >> 6, wl = t & 63, l16 = wl & 15, grp = wl >> 4;

    __shared__ __align__(16) u16 AT[2][64 * 64];
    __shared__ __align__(16) u16 BT[2][256 * 64];

    f32x4 acc[4][4];
    #pragma unroll
    for (int i = 0; i < 4; ++i)
        #pragma unroll
        for (int j = 0; j < 4; ++j) acc[i][j] = (f32x4){0.f, 0.f, 0.f, 0.f};

#define STAGE(bufi, kk) do {                                                  \
        _Pragma("unroll")                                                     \
        for (int it = 0; it < 2; ++it) {                                      \
            int lin = it * 256 + t;                                           \
            int row = lin >> 3, c = lin & 7;                                  \
            int cs = c ^ (row & 7);                                           \
            gload16(&A[(size_t)(m0 + row) * 256 + (kk) + cs * 8],             \
                    &AT[bufi][lin * 8]);                                      \
        }                                                                     \
        _Pragma("unroll")                                                     \
        for (int it = 0; it < 8; ++it) {                                      \
            int lin = it * 256 + t;                                           \
            int row = lin >> 3, c = lin & 7;                                  \
            int cs = c ^ (row & 7);                                           \
            gload16(&B[(size_t)(n0 + row) * 256 + (kk) + cs * 8],             \
                    &BT[bufi][lin * 8]);                                      \
        }                                                                     \
    } while (0)

    STAGE(0, 0);
    int cur = 0;
    for (int kt = 0; kt < 4; ++kt) {
        __syncthreads();   // drains vmcnt(0): buf[cur] staged; prev reads done
        if (kt < 3) STAGE(cur ^ 1, (kt + 1) * 64);   // in flight under compute
        #pragma unroll
        for (int ks = 0; ks < 2; ++ks) {
            bh8 af[4], bf[4];
            #pragma unroll
            for (int mi = 0; mi < 4; ++mi) {
                int row = mi * 16 + l16;
                int pc = (ks * 4 + grp) ^ (row & 7);
                af[mi] = *(const bh8*)&AT[cur][row * 64 + pc * 8];
            }
            #pragma unroll
            for (int ni = 0; ni < 4; ++ni) {
                int row = w * 64 + ni * 16 + l16;
                int pc = (ks * 4 + grp) ^ (row & 7);
                bf[ni] = *(const bh8*)&BT[cur][row * 64 + pc * 8];
            }
            #pragma unroll
            for (int mi = 0; mi < 4; ++mi)
                #pragma unroll
                for (int ni = 0; ni < 4; ++ni)
                    acc[mi][ni] = __builtin_amdgcn_mfma_f32_16x16x32_bf16(
                        af[mi], bf[ni], acc[mi][ni], 0, 0, 0);
        }
        cur ^= 1;
    }
#undef STAGE

    // epilogue: C[m][n], m = m0+mi*16+grp*4+r, n = n0+w*64+ni*16+l16
    #pragma unroll
    for (int mi = 0; mi < 4; ++mi)
        #pragma unroll
        for (int ni = 0; ni < 4; ++ni)
            #pragma unroll
            for (int r = 0; r < 4; ++r) {
                int m = m0 + mi*16 + grp*4 + r;
                int n = n0 + w*64 + ni*16 + l16;
                float val = acc[mi][ni][r];
                if (MODE == 0) {
                    u16* Yp = (u16*)Yv;
                    Yp[(size_t)(n >> 8) * arrsz + (size_t)m * 256 + (n & 255)] = f2b(val);
                } else {
                    float* Yf = (float*)Yv;
                    int bb = n >> lgS, s = n & ((1 << lgS) - 1);
                    Yf[(((size_t)bb * 256 + m) << lgS) + s] = val;
                }
            }
}

// ---------------- attention: one wave per (pixel, head) ----------------
__global__ __launch_bounds__(256) void k_attn(
    const u16* __restrict__ tK, const u16* __restrict__ tQ, const u16* __restrict__ tV,
    const u16* __restrict__ bK, const u16* __restrict__ bQ, const u16* __restrict__ bV,
    u16* __restrict__ tRet, u16* __restrict__ pat)
{
    const int pix = blockIdx.x;     // 0..4095
    const int b   = blockIdx.y;
    const int w   = threadIdx.x >> 6;
    const int wl  = threadIdx.x & 63;
    const int l16 = wl & 15, grp = wl >> 4;
    const int y = pix >> 6, x = pix & 63;

    __shared__ u16 Ssm[4][16][24];        // [wave][q][kpos], stride 48B
    __shared__ __align__(16) u16 Vsm[4][2][16][16]; // [wave][v-half][kpos][v16]

    // position p = l16: p=0 top pixel, p=1..9 bot neighbor, p>=10 pad
    const int p = l16;
    bool pvalid = false; int bpix = 0; const bool istop = (p == 0);
    if (p == 0) pvalid = true;
    else if (p < 10) {
        int pm = p - 1; int i = (pm * 11) >> 5; int j = pm - 3 * i;
        int by = 2 * y + i - 1, bx = 2 * x + j - 1;
        pvalid = ((unsigned)by < 128u) && ((unsigned)bx < 128u);
        bpix = by * 128 + bx;
    }
    const size_t topRow = ((size_t)b * 4096  + pix)  * 256;
    const size_t botRow = ((size_t)b * 16384 + bpix) * 256;
    const float scale = 0.17677669529663687f; // 1/sqrt(32)

    #pragma unroll
    for (int hi = 0; hi < 2; ++hi) {
        const int h = w + hi * 4;
        const size_t off = (istop ? topRow : botRow) + h * 32 + grp * 8;
        bh8 aQ = {}, aK = {}, vV = {};
        if (pvalid) {
            if (istop) {
                aQ = *(const bh8*)(tQ + off);
                aK = *(const bh8*)(tK + off);
                vV = *(const bh8*)(tV + off);
            } else {
                aQ = *(const bh8*)(bQ + off);
                aK = *(const bh8*)(bK + off);
                vV = *(const bh8*)(bV + off);
            }
        }
        // stage V rows (zeros for invalid rows): half = grp>>1, chunk (grp&1)*8
        *(bh8*)&Vsm[w][grp >> 1][p][(grp & 1) * 8] = vV;

        // S = Q.K^T   (A rows = query pos, B cols = key pos, k = d contiguous)
        f32x4 z = {0.f, 0.f, 0.f, 0.f};
        f32x4 sC = __builtin_amdgcn_mfma_f32_16x16x32_bf16(aQ, aK, z, 0, 0, 0);
        #pragma unroll
        for (int r = 0; r < 4; ++r)
            Ssm[w][grp * 4 + r][l16] = f2b(sC[r] * scale);

        // A_S: row q=l16, k-slots (grp,i<4) = kpos 4*grp+i ; slots i>=4 zero
        bh8 aS = {};
        *(bh4*)&aS = *(const bh4*)&Ssm[w][l16][grp * 4];

        // B_V: slot (grp,i<4) = V[kpos=4*grp+i][v], consistent with A_S labeling
        bh8 bv0 = {}, bv1 = {};
        #pragma unroll
        for (int j = 0; j < 4; ++j) {
            bv0[j] = (short)Vsm[w][0][grp * 4 + j][l16];
            bv1[j] = (short)Vsm[w][1][grp * 4 + j][l16];
        }
        f32x4 oc0 = __builtin_amdgcn_mfma_f32_16x16x32_bf16(aS, bv0, z, 0, 0, 0);
        f32x4 oc1 = __builtin_amdgcn_mfma_f32_16x16x32_bf16(aS, bv1, z, 0, 0, 0);

        // outputs: row q = grp*4+r, col v = l16 (+16 for oc1)
        if (grp == 0) {
            size_t o = topRow + (size_t)h * 32;
            tRet[o + l16]      = f2b(oc0[0]);
            tRet[o + 16 + l16] = f2b(oc1[0]);
        }
        #pragma unroll
        for (int r = 0; r < 4; ++r) {
            int q = grp * 4 + r;
            if (q >= 1 && q <= 9) {
                size_t base = ((((size_t)b * 8 + h) * 9 + (q - 1)) * 4096 + pix) * 32;
                pat[base + l16]      = f2b(oc0[r]);
                pat[base + 16 + l16] = f2b(oc1[r]);
            }
        }
    }
}

// ---------------- fold: pat [b][h][9][4096][32] -> botRet (B,16384,256) bf16 ----------------
__global__ __launch_bounds__(256) void k_fold(
    const u16* __restrict__ pat, u16* __restrict__ botRet)
{
    int tid = blockIdx.x * 256 + threadIdx.x;       // 1,048,576 threads
    int vchunk = tid & 3;                           // 8 v's each
    int ri = tid >> 2;                              // (b*16384 + bpix)*8 + h
    int b = ri >> 17;
    int bpix = (ri >> 3) & 16383;
    int h = ri & 7;
    int by = bpix >> 7, bx = bpix & 127;
    int v0 = vchunk * 8;

    float acc[8];
    #pragma unroll
    for (int e = 0; e < 8; ++e) acc[e] = 0.f;

    for (int iy = 0; iy < 3; ++iy) {
        int ty = by + 1 - iy;
        if (ty & 1) continue;
        int yy = ty >> 1;
        if ((unsigned)yy >= 64u) continue;
        for (int jx = 0; jx < 3; ++jx) {
            int tx = bx + 1 - jx;
            if (tx & 1) continue;
            int xx = tx >> 1;
            if ((unsigned)xx >= 64u) continue;
            int q = iy * 3 + jx;
            size_t addr = ((((size_t)b * 8 + h) * 9 + q) * 4096 + (yy * 64 + xx)) * 32 + v0;
            uint4 pv = *(const uint4*)&pat[addr];
            const u16* pp = (const u16*)&pv;
            #pragma unroll
            for (int e = 0; e < 8; ++e) acc[e] += b2f(pp[e]);
        }
    }
    u16 tmp[8];
    #pragma unroll
    for (int e = 0; e < 8; ++e) tmp[e] = f2b(acc[e]);
    *(uint4*)&botRet[((size_t)b * 16384 + bpix) * 256 + h * 32 + v0] = *(uint4*)tmp;
}

extern "C" void kernel_launch(void* const* d_in, const int* in_sizes, int n_in,
                              void* d_out, int out_size, void* d_ws, size_t ws_size,
                              hipStream_t stream) {
    const float* top_feat = (const float*)d_in[0];
    const float* bot_feat = (const float*)d_in[1];

    float* out     = (float*)d_out;
    float* top_out = out;                            // (2,256,64,64)
    float* bot_out = out + (size_t)2 * 256 * 4096;   // (2,256,128,128)

    const size_t TOPU = (size_t)2 * 4096  * 256;   // ushort counts
    const size_t BOTU = (size_t)2 * 16384 * 256;
    char* p = (char*)d_ws;
    u16* Wb     = (u16*)p;  p += (size_t)8 * 65536 * 2;   // 1.0 MB
    u16* topT   = (u16*)p;  p += TOPU * 2;                // 4.2 MB
    u16* botT   = (u16*)p;  p += BOTU * 2;                // 16.8 MB
    u16* tK     = (u16*)p;  p += TOPU * 2;
    u16* tQ     = (u16*)p;  p += TOPU * 2;
    u16* tV     = (u16*)p;  p += TOPU * 2;                // 12.6 MB
    u16* bK     = (u16*)p;  p += BOTU * 2;
    u16* bQ     = (u16*)p;  p += BOTU * 2;
    u16* bV     = (u16*)p;  p += BOTU * 2;                // 50.3 MB
    u16* tRet   = (u16*)p;  p += TOPU * 2;                // 4.2 MB
    u16* pat    = (u16*)p;  p += (size_t)2*8*9*4096*32*2; // 37.7 MB
    u16* botRet = (u16*)p;  p += BOTU * 2;                // 16.8 MB  (total ~143.7 MB)

    dim3 blk(256);

    // weights -> bf16 (order: tK,tQ,tV,bK,bQ,bV,tFuse,bFuse)
    k_cvt_w<<<dim3(64, 8), blk, 0, stream>>>(
        (const float*)d_in[2], (const float*)d_in[3], (const float*)d_in[4],
        (const float*)d_in[5], (const float*)d_in[6], (const float*)d_in[7],
        (const float*)d_in[8], (const float*)d_in[9], Wb);

    // feat transpose+convert
    k_transpose_cvt<<<dim3(64, 4, 2),  blk, 0, stream>>>(top_feat, topT, 4096);
    k_transpose_cvt<<<dim3(256, 4, 2), blk, 0, stream>>>(bot_feat, botT, 16384);

    // fused QKV projections (N = 768 = [K|Q|V] each 256 wide)
    k_gemm<0><<<dim3(3, 128), blk, 0, stream>>>(topT, Wb,              (void*)tK, TOPU, 0);
    k_gemm<0><<<dim3(3, 512), blk, 0, stream>>>(botT, Wb + 3*65536,    (void*)bK, BOTU, 0);

    // attention
    k_attn<<<dim3(4096, 2), blk, 0, stream>>>(tK, tQ, tV, bK, bQ, bV, tRet, pat);

    // fold bot windows
    k_fold<<<dim3(4096), blk, 0, stream>>>(pat, botRet);

    // fuse GEMMs -> fp32 channel-major outputs
    k_gemm<1><<<dim3(32, 4),  blk, 0, stream>>>(Wb + 6*65536, tRet,   (void*)top_out, 0, 12);
    k_gemm<1><<<dim3(128, 4), blk, 0, stream>>>(Wb + 7*65536, botRet, (void*)bot_out, 0, 14);
}